// Round 4
// baseline (304.146 us; speedup 1.0000x reference)
//
#include <hip/hip_runtime.h>
#include <stdint.h>

// Problem constants
#define MM 4096   // B*S
#define SS 1024   // S
#define DD 1024   // D
#define HH 16     // heads
#define DKK 64    // head dim
#define BHH 64    // B*H

typedef __bf16 bf16x8 __attribute__((ext_vector_type(8)));
typedef __bf16 bf16x4 __attribute__((ext_vector_type(4)));
typedef float  f32x4  __attribute__((ext_vector_type(4)));

__device__ __forceinline__ void gload_lds16(const void* g, void* l) {
  // async global->LDS, 16B per lane; LDS dest is wave-uniform base + lane*16
  __builtin_amdgcn_global_load_lds(
      (__attribute__((address_space(1))) void*)g,
      (__attribute__((address_space(3))) void*)l, 16, 0, 0);
}

// ---------------- pass 0: f32 -> bf16 for q,k,v (vectorized, G13) ----------
__global__ __launch_bounds__(256) void cvt3(const float* __restrict__ q,
                                            const float* __restrict__ k,
                                            const float* __restrict__ v,
                                            __bf16* __restrict__ X3) {
  const float* src = (blockIdx.y == 0) ? q : ((blockIdx.y == 1) ? k : v);
  size_t i = ((size_t)blockIdx.x * 256 + threadIdx.x) * 8;
  float4 a = *(const float4*)(src + i);
  float4 b = *(const float4*)(src + i + 4);
  bf16x8 r;
  r[0] = (__bf16)a.x; r[1] = (__bf16)a.y; r[2] = (__bf16)a.z; r[3] = (__bf16)a.w;
  r[4] = (__bf16)b.x; r[5] = (__bf16)b.y; r[6] = (__bf16)b.z; r[7] = (__bf16)b.w;
  *(bf16x8*)(X3 + (size_t)blockIdx.y * MM * DD + i) = r;
}

// ---------------- pass 1: fold per-head FF into projection weight ----------
// Wc[h*64+j][i] = sum_d Wf[j][d] * W[h*64+d][i];  bc = Wf@b_head + bf
__global__ __launch_bounds__(256) void wcombine(const float* __restrict__ W,
                                                const float* __restrict__ bias,
                                                const float* __restrict__ Wf,
                                                const float* __restrict__ bf_,
                                                __bf16* __restrict__ Wc,
                                                float* __restrict__ bc) {
  int i = blockIdx.x * 256 + threadIdx.x;  // input col
  int o = blockIdx.y;                      // output row
  int h = o >> 6, j = o & 63;
  const float* wfr = Wf + j * DKK;
  float acc = 0.f;
#pragma unroll 8
  for (int d = 0; d < DKK; ++d)
    acc += wfr[d] * W[(size_t)(h * DKK + d) * DD + i];
  Wc[(size_t)o * DD + i] = (__bf16)acc;
  if (blockIdx.x == 0 && threadIdx.x == 0) {
    float bb = bf_[j];
    for (int d = 0; d < DKK; ++d) bb += wfr[d] * bias[h * DKK + d];
    bc[o] = bb;
  }
}

// ---------------- pass 2: fused 3x GEMM+bias+ReLU, C = relu(X@Wc^T + bc) ---
// z=0: Q rows [m][o];  z=1: K rows [m][o];  z=2: V stored TRANSPOSED
// per head: Vt[(bh*64+dk)*1024 + s]  (so attention PV reads are contiguous)
__global__ __launch_bounds__(256) void gemm3(const __bf16* __restrict__ X3,
                                             const __bf16* __restrict__ Wc3,
                                             const float* __restrict__ bc3,
                                             __bf16* __restrict__ QKV) {
  __shared__ __bf16 As[128 * 64];
  __shared__ __bf16 Bs[128 * 64];
  const int z = blockIdx.z;
  const __bf16* A  = X3  + (size_t)z * MM * DD;
  const __bf16* Bt = Wc3 + (size_t)z * DD * DD;
  const float* bias = bc3 + z * DD;
  __bf16* C = QKV + (size_t)z * MM * DD;

  const int tid = threadIdx.x;
  const int wave = tid >> 6, lane = tid & 63;
  const int l15 = lane & 15, l4 = lane >> 4;
  const int bm = blockIdx.x * 128;
  const int bn = blockIdx.y * 128;
  const int wr = (wave >> 1) * 64;
  const int wc = (wave & 1) * 64;

  f32x4 acc[4][4] = {};

  const int srow = wave * 8 + (lane >> 3);  // staging row within 32-row issue
  const int scol = (lane & 7) * 8;

  for (int kt = 0; kt < DD; kt += 64) {
    __syncthreads();
#pragma unroll
    for (int j = 0; j < 4; ++j) {
      int row = j * 32 + srow;
      gload_lds16(A  + (size_t)(bm + row) * DD + kt + scol, As + j * 2048 + wave * 512);
      gload_lds16(Bt + (size_t)(bn + row) * DD + kt + scol, Bs + j * 2048 + wave * 512);
    }
    asm volatile("s_waitcnt vmcnt(0)" ::: "memory");
    __syncthreads();
#pragma unroll
    for (int ks = 0; ks < 2; ++ks) {
      bf16x8 af[4], bfr[4];
#pragma unroll
      for (int mi = 0; mi < 4; ++mi)
        af[mi] = *(const bf16x8*)(As + (wr + mi * 16 + l15) * 64 + ks * 32 + l4 * 8);
#pragma unroll
      for (int ni = 0; ni < 4; ++ni)
        bfr[ni] = *(const bf16x8*)(Bs + (wc + ni * 16 + l15) * 64 + ks * 32 + l4 * 8);
#pragma unroll
      for (int mi = 0; mi < 4; ++mi)
#pragma unroll
        for (int ni = 0; ni < 4; ++ni)
          acc[mi][ni] = __builtin_amdgcn_mfma_f32_16x16x32_bf16(af[mi], bfr[ni], acc[mi][ni], 0, 0, 0);
    }
  }

  // epilogue: bias + relu + bf16 store (z==2 -> transposed per-head layout)
#pragma unroll
  for (int ni = 0; ni < 4; ++ni) {
    int n = bn + wc + ni * 16 + l15;
    float bb = bias[n];
#pragma unroll
    for (int mi = 0; mi < 4; ++mi) {
      if (z != 2) {
#pragma unroll
        for (int r = 0; r < 4; ++r) {
          int m = bm + wr + mi * 16 + l4 * 4 + r;
          float vv = acc[mi][ni][r] + bb;
          vv = vv > 0.f ? vv : 0.f;
          C[(size_t)m * DD + n] = (__bf16)vv;
        }
      } else {
        int m0 = bm + wr + mi * 16 + l4 * 4;
        int b = m0 >> 10, s0 = m0 & 1023;
        int h = n >> 6, dk = n & 63;
        bf16x4 pk;
#pragma unroll
        for (int r = 0; r < 4; ++r) {
          float vv = acc[mi][ni][r] + bb;
          vv = vv > 0.f ? vv : 0.f;
          pk[r] = (__bf16)vv;
        }
        *(bf16x4*)(C + ((size_t)(b * HH + h) * DKK + dk) * SS + s0) = pk;
      }
    }
  }
}

// ---------------- pass 3: flash attention + fused Wo epilogue --------------
// grid: (qt=S/64, bh=B*H). block 256 = 4 waves, each wave owns 16 q rows.
__global__ __launch_bounds__(256) void attn_kernel(
    const __bf16* __restrict__ Q,   // [4096][1024]
    const __bf16* __restrict__ K,   // [4096][1024]
    const __bf16* __restrict__ Vt,  // [64 bh][64 dk][1024 s]
    const int* __restrict__ mask,   // [64][1024]
    const float* __restrict__ Wo,   // [64][64]
    const float* __restrict__ bo,   // [64]
    float* __restrict__ out)        // [4][1024][1024]
{
  __shared__ __bf16 Qs[64 * 64];
  __shared__ __bf16 Ks[64 * 64];
  __shared__ __bf16 Vs[64 * 64];     // V^T tile: [dk][key]
  __shared__ __bf16 Pw[4][16 * 64];  // per-wave P staging
  __shared__ __bf16 Wos[64 * 64];

  const int tid = threadIdx.x;
  const int wave = tid >> 6, lane = tid & 63;
  const int l15 = lane & 15, l4 = lane >> 4;
  const int qt = blockIdx.x;
  const int bh = blockIdx.y;
  const int b = bh >> 4, h = bh & 15;

  const __bf16* Qbase = Q + ((size_t)b * SS + qt * 64) * DD + h * 64;
  const __bf16* Kbase = K + (size_t)b * SS * DD + h * 64;
  const __bf16* Vbase = Vt + (size_t)bh * DKK * SS;

  // stage Wo -> LDS bf16 (read after many barriers; safe)
  for (int t = tid; t < 64 * 64; t += 256) Wos[t] = (__bf16)Wo[t];

  // stage Q tile (64 rows x 64 dk)
  {
    int cr = wave * 8 + (lane >> 3);
    int cc = (lane & 7) * 8;
#pragma unroll
    for (int j = 0; j < 2; ++j)
      gload_lds16(Qbase + (size_t)(j * 32 + cr) * DD + cc, Qs + j * 2048 + wave * 512);
  }

  f32x4 o_acc[4] = {};
  float mrow[4], lrow[4];
#pragma unroll
  for (int r = 0; r < 4; ++r) { mrow[r] = -1e30f; lrow[r] = 0.f; }

  for (int kt = 0; kt < SS / 64; ++kt) {
    __syncthreads();  // previous tile's PV reads done
    {
      int cr = wave * 8 + (lane >> 3);
      int cc = (lane & 7) * 8;
#pragma unroll
      for (int j = 0; j < 2; ++j) {
        int row = j * 32 + cr;
        gload_lds16(Kbase + (size_t)(kt * 64 + row) * DD + cc, Ks + j * 2048 + wave * 512);
        gload_lds16(Vbase + (size_t)row * SS + kt * 64 + cc,   Vs + j * 2048 + wave * 512);
      }
    }
    asm volatile("s_waitcnt vmcnt(0)" ::: "memory");
    __syncthreads();

    // S = Q K^T for 16 q rows x 64 keys
    f32x4 sc[4] = {};
#pragma unroll
    for (int ks = 0; ks < 2; ++ks) {
      bf16x8 aq = *(const bf16x8*)(Qs + (wave * 16 + l15) * 64 + ks * 32 + l4 * 8);
#pragma unroll
      for (int ni = 0; ni < 4; ++ni) {
        bf16x8 kf = *(const bf16x8*)(Ks + (ni * 16 + l15) * 64 + ks * 32 + l4 * 8);
        sc[ni] = __builtin_amdgcn_mfma_f32_16x16x32_bf16(aq, kf, sc[ni], 0, 0, 0);
      }
    }
    // scale + mask (replace with -10000 where mask==0, per reference)
#pragma unroll
    for (int ni = 0; ni < 4; ++ni) {
      int key = kt * 64 + ni * 16 + l15;
      int mv = mask[bh * SS + key];
#pragma unroll
      for (int r = 0; r < 4; ++r) {
        float s = sc[ni][r] * 0.125f;
        sc[ni][r] = (mv == 0) ? -10000.f : s;
      }
    }
    // online softmax (16-lane row reduce)
    float alpha[4];
#pragma unroll
    for (int r = 0; r < 4; ++r) {
      float v = fmaxf(fmaxf(sc[0][r], sc[1][r]), fmaxf(sc[2][r], sc[3][r]));
      v = fmaxf(v, __shfl_xor(v, 1));
      v = fmaxf(v, __shfl_xor(v, 2));
      v = fmaxf(v, __shfl_xor(v, 4));
      v = fmaxf(v, __shfl_xor(v, 8));
      float mnew = fmaxf(mrow[r], v);
      alpha[r] = __expf(mrow[r] - mnew);
      mrow[r] = mnew;
      float s = 0.f;
#pragma unroll
      for (int ni = 0; ni < 4; ++ni) {
        float p = __expf(sc[ni][r] - mnew);
        sc[ni][r] = p;
        s += p;
      }
      s += __shfl_xor(s, 1); s += __shfl_xor(s, 2);
      s += __shfl_xor(s, 4); s += __shfl_xor(s, 8);
      lrow[r] = lrow[r] * alpha[r] + s;
    }
    // P -> per-wave LDS (D-layout scatter), then read back as A fragments
#pragma unroll
    for (int ni = 0; ni < 4; ++ni)
#pragma unroll
      for (int r = 0; r < 4; ++r)
        Pw[wave][(l4 * 4 + r) * 64 + ni * 16 + l15] = (__bf16)sc[ni][r];
    asm volatile("" ::: "memory");
    // rescale O
#pragma unroll
    for (int ni = 0; ni < 4; ++ni)
#pragma unroll
      for (int r = 0; r < 4; ++r) o_acc[ni][r] *= alpha[r];
    // O += P V
#pragma unroll
    for (int ks = 0; ks < 2; ++ks) {
      bf16x8 ap = *(const bf16x8*)(&Pw[wave][l15 * 64 + ks * 32 + l4 * 8]);
#pragma unroll
      for (int ni = 0; ni < 4; ++ni) {
        bf16x8 vf = *(const bf16x8*)(Vs + (ni * 16 + l15) * 64 + ks * 32 + l4 * 8);
        o_acc[ni] = __builtin_amdgcn_mfma_f32_16x16x32_bf16(ap, vf, o_acc[ni], 0, 0, 0);
      }
    }
  }

  // normalize, then fused per-head Wo: final = (O/l) @ Wo^T + bo
#pragma unroll
  for (int ni = 0; ni < 4; ++ni)
#pragma unroll
    for (int r = 0; r < 4; ++r)
      Pw[wave][(l4 * 4 + r) * 64 + ni * 16 + l15] = (__bf16)(o_acc[ni][r] / lrow[r]);
  asm volatile("" ::: "memory");
  f32x4 facc[4] = {};
#pragma unroll
  for (int ks = 0; ks < 2; ++ks) {
    bf16x8 ao = *(const bf16x8*)(&Pw[wave][l15 * 64 + ks * 32 + l4 * 8]);
#pragma unroll
    for (int ni = 0; ni < 4; ++ni) {
      bf16x8 wf = *(const bf16x8*)(Wos + (ni * 16 + l15) * 64 + ks * 32 + l4 * 8);
      facc[ni] = __builtin_amdgcn_mfma_f32_16x16x32_bf16(ao, wf, facc[ni], 0, 0, 0);
    }
  }
#pragma unroll
  for (int ni = 0; ni < 4; ++ni) {
    int j = ni * 16 + l15;
    float bb = bo[j];
#pragma unroll
    for (int r = 0; r < 4; ++r) {
      int qrow = qt * 64 + wave * 16 + l4 * 4 + r;
      out[((size_t)b * SS + qrow) * DD + h * 64 + j] = facc[ni][r] + bb;
    }
  }
}

// ---------------- host ----------------
extern "C" void kernel_launch(void* const* d_in, const int* in_sizes, int n_in,
                              void* d_out, int out_size, void* d_ws, size_t ws_size,
                              hipStream_t stream) {
  const float* q   = (const float*)d_in[0];
  const float* k   = (const float*)d_in[1];
  const float* v   = (const float*)d_in[2];
  const int*   mask= (const int*)d_in[3];
  const float* Wq  = (const float*)d_in[4];
  const float* bq  = (const float*)d_in[5];
  const float* Wk  = (const float*)d_in[6];
  const float* bk  = (const float*)d_in[7];
  const float* Wv  = (const float*)d_in[8];
  const float* bv  = (const float*)d_in[9];
  const float* Wqf = (const float*)d_in[10];
  const float* bqf = (const float*)d_in[11];
  const float* Wkf = (const float*)d_in[12];
  const float* bkf = (const float*)d_in[13];
  const float* Wvf = (const float*)d_in[14];
  const float* bvf = (const float*)d_in[15];
  const float* Wo  = (const float*)d_in[16];
  const float* bo  = (const float*)d_in[17];
  float* out = (float*)d_out;

  // workspace layout
  char* p = (char*)d_ws;
  __bf16* X3  = (__bf16*)p; p += (size_t)3 * MM * DD * 2;   // 24 MB
  __bf16* Wc3 = (__bf16*)p; p += (size_t)3 * DD * DD * 2;   // 6 MB
  __bf16* QKV = (__bf16*)p; p += (size_t)3 * MM * DD * 2;   // 24 MB
  float*  bc3 = (float*)p;  p += (size_t)3 * DD * 4;        // 12 KB
  if ((size_t)(p - (char*)d_ws) > ws_size) return;  // workspace too small

  cvt3<<<dim3(2048, 3), 256, 0, stream>>>(q, k, v, X3);
  wcombine<<<dim3(4, 1024), 256, 0, stream>>>(Wq, bq, Wqf, bqf, Wc3, bc3);
  wcombine<<<dim3(4, 1024), 256, 0, stream>>>(Wk, bk, Wkf, bkf, Wc3 + (size_t)DD * DD, bc3 + DD);
  wcombine<<<dim3(4, 1024), 256, 0, stream>>>(Wv, bv, Wvf, bvf, Wc3 + (size_t)2 * DD * DD, bc3 + 2 * DD);
  gemm3<<<dim3(32, 8, 3), 256, 0, stream>>>(X3, Wc3, bc3, QKV);
  attn_kernel<<<dim3(16, 64), 256, 0, stream>>>(
      QKV, QKV + (size_t)MM * DD, QKV + (size_t)2 * MM * DD, mask, Wo, bo, out);
}

// Round 5
// 269.452 us; speedup vs baseline: 1.1288x; 1.1288x over previous
//
#include <hip/hip_runtime.h>
#include <stdint.h>

// Problem constants
#define MM 4096   // B*S
#define SS 1024   // S
#define DD 1024   // D
#define HH 16     // heads
#define DKK 64    // head dim

typedef __bf16 bf16x8 __attribute__((ext_vector_type(8)));
typedef __bf16 bf16x4 __attribute__((ext_vector_type(4)));
typedef float  f32x4  __attribute__((ext_vector_type(4)));

__device__ __forceinline__ void gload_lds16(const void* g, void* l) {
  // async global->LDS, 16B per lane; LDS dest is wave-uniform base + lane*16
  __builtin_amdgcn_global_load_lds(
      (__attribute__((address_space(1))) void*)g,
      (__attribute__((address_space(3))) void*)l, 16, 0, 0);
}

// Swizzled element offset within a [rows][64] bf16 tile (row = 128B = 8 chunks
// of 16B). chunk' = chunk ^ (row&7) spreads the 8 rows of a stripe across all
// 32 banks -> conflict-free ds_read_b128 column reads.  (T2 / m201 pattern)
#define LSW(row, ch) ((row) * 64 + ((((ch) ^ ((row) & 7)) << 3)))

// ---------------- pass 0+1 fused: cvt3 + 3x wcombine in ONE launch ---------
// blocks [0,6144): f32->bf16 convert of q/k/v (2048 blocks each)
// blocks [6144,18432): Wc[z][o][i] = sum_d Wf_z[j][d]*W_z[h*64+d][i] (FF fold)
__global__ __launch_bounds__(256) void prep(
    const float* __restrict__ q, const float* __restrict__ k,
    const float* __restrict__ v,
    const float* __restrict__ Wq, const float* __restrict__ bq,
    const float* __restrict__ Wk, const float* __restrict__ bk,
    const float* __restrict__ Wv, const float* __restrict__ bv,
    const float* __restrict__ Wqf, const float* __restrict__ bqf,
    const float* __restrict__ Wkf, const float* __restrict__ bkf,
    const float* __restrict__ Wvf, const float* __restrict__ bvf,
    __bf16* __restrict__ X3, __bf16* __restrict__ Wc3,
    float* __restrict__ bc3) {
  int blk = blockIdx.x;
  if (blk < 6144) {
    int z = blk >> 11;          // 0,1,2
    int bx = blk & 2047;
    const float* src = (z == 0) ? q : ((z == 1) ? k : v);
    size_t i = ((size_t)bx * 256 + threadIdx.x) * 8;
    float4 a = *(const float4*)(src + i);
    float4 b = *(const float4*)(src + i + 4);
    bf16x8 r;
    r[0] = (__bf16)a.x; r[1] = (__bf16)a.y; r[2] = (__bf16)a.z; r[3] = (__bf16)a.w;
    r[4] = (__bf16)b.x; r[5] = (__bf16)b.y; r[6] = (__bf16)b.z; r[7] = (__bf16)b.w;
    *(bf16x8*)(X3 + (size_t)z * MM * DD + i) = r;
  } else {
    int t = blk - 6144;
    int z = t >> 12;            // /4096
    int wb = t & 4095;
    int i = (wb & 3) * 256 + threadIdx.x;  // input col
    int o = wb >> 2;                       // output row
    const float* W   = (z == 0) ? Wq  : ((z == 1) ? Wk  : Wv);
    const float* bs  = (z == 0) ? bq  : ((z == 1) ? bk  : bv);
    const float* Wf  = (z == 0) ? Wqf : ((z == 1) ? Wkf : Wvf);
    const float* bf_ = (z == 0) ? bqf : ((z == 1) ? bkf : bvf);
    int h = o >> 6, j = o & 63;
    const float* wfr = Wf + j * DKK;
    float acc = 0.f;
#pragma unroll 8
    for (int d = 0; d < DKK; ++d)
      acc += wfr[d] * W[(size_t)(h * DKK + d) * DD + i];
    Wc3[(size_t)z * DD * DD + (size_t)o * DD + i] = (__bf16)acc;
    if ((wb & 3) == 0 && threadIdx.x == 0) {
      float bb = bf_[j];
      for (int d = 0; d < DKK; ++d) bb += wfr[d] * bs[h * DKK + d];
      bc3[z * DD + o] = bb;
    }
  }
}

// ---------------- pass 2: fused 3x GEMM+bias+ReLU, C = relu(X@Wc^T + bc) ---
// z=0: Q rows [m][o];  z=1: K rows [m][o];  z=2: V stored TRANSPOSED
// per head: Vt[(bh*64+dk)*1024 + s]  (so attention PV reads are contiguous)
__global__ __launch_bounds__(256) void gemm3(const __bf16* __restrict__ X3,
                                             const __bf16* __restrict__ Wc3,
                                             const float* __restrict__ bc3,
                                             __bf16* __restrict__ QKV) {
  __shared__ __bf16 As[128 * 64];
  __shared__ __bf16 Bs[128 * 64];
  const int z = blockIdx.z;
  const __bf16* A  = X3  + (size_t)z * MM * DD;
  const __bf16* Bt = Wc3 + (size_t)z * DD * DD;
  const float* bias = bc3 + z * DD;
  __bf16* C = QKV + (size_t)z * MM * DD;

  const int tid = threadIdx.x;
  const int wave = tid >> 6, lane = tid & 63;
  const int l15 = lane & 15, l4 = lane >> 4;
  const int bm = blockIdx.x * 128;
  const int bn = blockIdx.y * 128;
  const int wr = (wave >> 1) * 64;
  const int wc = (wave & 1) * 64;

  f32x4 acc[4][4] = {};

  const int srow = wave * 8 + (lane >> 3);  // staging row within 32-row issue
  const int scol = (lane & 7) * 8;

  for (int kt = 0; kt < DD; kt += 64) {
    __syncthreads();
#pragma unroll
    for (int j = 0; j < 4; ++j) {
      int row = j * 32 + srow;
      gload_lds16(A  + (size_t)(bm + row) * DD + kt + scol, As + j * 2048 + wave * 512);
      gload_lds16(Bt + (size_t)(bn + row) * DD + kt + scol, Bs + j * 2048 + wave * 512);
    }
    asm volatile("s_waitcnt vmcnt(0)" ::: "memory");
    __syncthreads();
#pragma unroll
    for (int ks = 0; ks < 2; ++ks) {
      bf16x8 af[4], bfr[4];
#pragma unroll
      for (int mi = 0; mi < 4; ++mi)
        af[mi] = *(const bf16x8*)(As + (wr + mi * 16 + l15) * 64 + ks * 32 + l4 * 8);
#pragma unroll
      for (int ni = 0; ni < 4; ++ni)
        bfr[ni] = *(const bf16x8*)(Bs + (wc + ni * 16 + l15) * 64 + ks * 32 + l4 * 8);
#pragma unroll
      for (int mi = 0; mi < 4; ++mi)
#pragma unroll
        for (int ni = 0; ni < 4; ++ni)
          acc[mi][ni] = __builtin_amdgcn_mfma_f32_16x16x32_bf16(af[mi], bfr[ni], acc[mi][ni], 0, 0, 0);
    }
  }

  // epilogue: bias + relu + bf16 store (z==2 -> transposed per-head layout)
#pragma unroll
  for (int ni = 0; ni < 4; ++ni) {
    int n = bn + wc + ni * 16 + l15;
    float bb = bias[n];
#pragma unroll
    for (int mi = 0; mi < 4; ++mi) {
      if (z != 2) {
#pragma unroll
        for (int r = 0; r < 4; ++r) {
          int m = bm + wr + mi * 16 + l4 * 4 + r;
          float vv = acc[mi][ni][r] + bb;
          vv = vv > 0.f ? vv : 0.f;
          C[(size_t)m * DD + n] = (__bf16)vv;
        }
      } else {
        int m0 = bm + wr + mi * 16 + l4 * 4;
        int b = m0 >> 10, s0 = m0 & 1023;
        int h = n >> 6, dk = n & 63;
        bf16x4 pk;
#pragma unroll
        for (int r = 0; r < 4; ++r) {
          float vv = acc[mi][ni][r] + bb;
          vv = vv > 0.f ? vv : 0.f;
          pk[r] = (__bf16)vv;
        }
        *(bf16x4*)(C + ((size_t)(b * HH + h) * DKK + dk) * SS + s0) = pk;
      }
    }
  }
}

// ---------------- pass 3: flash attention + fused Wo epilogue --------------
// grid: 1024 blocks (qt x bh), XCD-swizzled. 4 waves, 16 q rows each.
// All LDS tiles XOR-swizzled (T2): staging pre-swizzles the GLOBAL source
// chunk (LDS dest stays linear, rule #21); reads apply the same XOR.
__global__ __launch_bounds__(256) void attn_kernel(
    const __bf16* __restrict__ Q,   // [4096][1024]
    const __bf16* __restrict__ K,   // [4096][1024]
    const __bf16* __restrict__ Vt,  // [64 bh][64 dk][1024 s]
    const int* __restrict__ mask,   // [64][1024]
    const float* __restrict__ Wo,   // [64][64]
    const float* __restrict__ bo,   // [64]
    float* __restrict__ out)        // [4][1024][1024]
{
  __shared__ __bf16 Qs[64 * 64];
  __shared__ __bf16 Ks[64 * 64];
  __shared__ __bf16 Vs[64 * 64];     // V^T tile: [dk][key]
  __shared__ __bf16 Pw[4][16 * 64];  // per-wave P staging
  __shared__ __bf16 Wos[64 * 64];

  const int tid = threadIdx.x;
  const int wave = tid >> 6, lane = tid & 63;
  const int l15 = lane & 15, l4 = lane >> 4;

  // T1: XCD-aware remap (1024 blocks, 1024%8==0 -> simple bijection).
  // XCD c gets bh in [c*8, c*8+8) with all 16 qt -> K/V panels L2-local.
  const int lin = blockIdx.x + 16 * blockIdx.y;
  const int swz = (lin & 7) * 128 + (lin >> 3);
  const int qt = swz & 15;
  const int bh = swz >> 4;
  const int b = bh >> 4, h = bh & 15;

  const __bf16* Qbase = Q + ((size_t)b * SS + qt * 64) * DD + h * 64;
  const __bf16* Kbase = K + (size_t)b * SS * DD + h * 64;
  const __bf16* Vbase = Vt + (size_t)bh * DKK * SS;

  // stage Wo -> LDS bf16, swizzled store (reads are swizzled b128 later)
  for (int t = tid; t < 64 * 64; t += 256) {
    int row = t >> 6, col = t & 63;
    Wos[row * 64 + ((((col >> 3) ^ (row & 7)) << 3) | (col & 7))] = (__bf16)Wo[t];
  }

  // staging address map: lane l covers LDS chunk (l&7) of row (..+ l>>3);
  // row&7 == l>>3 always, so pre-swizzled global chunk = (l&7) ^ (l>>3).
  const int cr = wave * 8 + (lane >> 3);
  const int scol = (((lane & 7) ^ (lane >> 3)) * 8);

  // stage Q tile (64 rows x 64 dk)
#pragma unroll
  for (int j = 0; j < 2; ++j)
    gload_lds16(Qbase + (size_t)(j * 32 + cr) * DD + scol, Qs + j * 2048 + wave * 512);

  f32x4 o_acc[4] = {};
  float mrow[4], lrow[4];
#pragma unroll
  for (int r = 0; r < 4; ++r) { mrow[r] = -1e30f; lrow[r] = 0.f; }

  for (int kt = 0; kt < SS / 64; ++kt) {
    __syncthreads();  // previous tile's PV reads done
#pragma unroll
    for (int j = 0; j < 2; ++j) {
      int row = j * 32 + cr;
      gload_lds16(Kbase + (size_t)(kt * 64 + row) * DD + scol, Ks + j * 2048 + wave * 512);
      gload_lds16(Vbase + (size_t)row * SS + kt * 64 + scol,   Vs + j * 2048 + wave * 512);
    }
    asm volatile("s_waitcnt vmcnt(0)" ::: "memory");
    __syncthreads();

    // S = Q K^T for 16 q rows x 64 keys (swizzled fragment reads)
    f32x4 sc[4] = {};
#pragma unroll
    for (int ks = 0; ks < 2; ++ks) {
      bf16x8 aq = *(const bf16x8*)(Qs + LSW(wave * 16 + l15, ks * 4 + l4));
#pragma unroll
      for (int ni = 0; ni < 4; ++ni) {
        bf16x8 kf = *(const bf16x8*)(Ks + LSW(ni * 16 + l15, ks * 4 + l4));
        sc[ni] = __builtin_amdgcn_mfma_f32_16x16x32_bf16(aq, kf, sc[ni], 0, 0, 0);
      }
    }
    // scale + mask (replace with -10000 where mask==0, per reference)
#pragma unroll
    for (int ni = 0; ni < 4; ++ni) {
      int key = kt * 64 + ni * 16 + l15;
      int mv = mask[bh * SS + key];
#pragma unroll
      for (int r = 0; r < 4; ++r) {
        float s = sc[ni][r] * 0.125f;
        sc[ni][r] = (mv == 0) ? -10000.f : s;
      }
    }
    // online softmax (16-lane row reduce)
    float alpha[4];
#pragma unroll
    for (int r = 0; r < 4; ++r) {
      float v = fmaxf(fmaxf(sc[0][r], sc[1][r]), fmaxf(sc[2][r], sc[3][r]));
      v = fmaxf(v, __shfl_xor(v, 1));
      v = fmaxf(v, __shfl_xor(v, 2));
      v = fmaxf(v, __shfl_xor(v, 4));
      v = fmaxf(v, __shfl_xor(v, 8));
      float mnew = fmaxf(mrow[r], v);
      alpha[r] = __expf(mrow[r] - mnew);
      mrow[r] = mnew;
      float s = 0.f;
#pragma unroll
      for (int ni = 0; ni < 4; ++ni) {
        float p = __expf(sc[ni][r] - mnew);
        sc[ni][r] = p;
        s += p;
      }
      s += __shfl_xor(s, 1); s += __shfl_xor(s, 2);
      s += __shfl_xor(s, 4); s += __shfl_xor(s, 8);
      lrow[r] = lrow[r] * alpha[r] + s;
    }
    // P -> per-wave LDS (swizzled scatter; writes stay 2-way = free)
#pragma unroll
    for (int ni = 0; ni < 4; ++ni)
#pragma unroll
      for (int r = 0; r < 4; ++r) {
        int row = l4 * 4 + r;
        int ch = 2 * ni + (l15 >> 3);
        Pw[wave][row * 64 + (((ch ^ (row & 7)) << 3) | (l15 & 7))] = (__bf16)sc[ni][r];
      }
    asm volatile("" ::: "memory");
    // rescale O
#pragma unroll
    for (int ni = 0; ni < 4; ++ni)
#pragma unroll
      for (int r = 0; r < 4; ++r) o_acc[ni][r] *= alpha[r];
    // O += P V  (swizzled reads)
#pragma unroll
    for (int ks = 0; ks < 2; ++ks) {
      bf16x8 ap = *(const bf16x8*)(&Pw[wave][LSW(l15, ks * 4 + l4)]);
#pragma unroll
      for (int ni = 0; ni < 4; ++ni) {
        bf16x8 vf = *(const bf16x8*)(Vs + LSW(ni * 16 + l15, ks * 4 + l4));
        o_acc[ni] = __builtin_amdgcn_mfma_f32_16x16x32_bf16(ap, vf, o_acc[ni], 0, 0, 0);
      }
    }
  }

  // normalize, then fused per-head Wo: final = (O/l) @ Wo^T + bo
#pragma unroll
  for (int ni = 0; ni < 4; ++ni)
#pragma unroll
    for (int r = 0; r < 4; ++r) {
      int row = l4 * 4 + r;
      int ch = 2 * ni + (l15 >> 3);
      Pw[wave][row * 64 + (((ch ^ (row & 7)) << 3) | (l15 & 7))] =
          (__bf16)(o_acc[ni][r] / lrow[r]);
    }
  asm volatile("" ::: "memory");
  f32x4 facc[4] = {};
#pragma unroll
  for (int ks = 0; ks < 2; ++ks) {
    bf16x8 ao = *(const bf16x8*)(&Pw[wave][LSW(l15, ks * 4 + l4)]);
#pragma unroll
    for (int ni = 0; ni < 4; ++ni) {
      bf16x8 wf = *(const bf16x8*)(Wos + LSW(ni * 16 + l15, ks * 4 + l4));
      facc[ni] = __builtin_amdgcn_mfma_f32_16x16x32_bf16(ao, wf, facc[ni], 0, 0, 0);
    }
  }
#pragma unroll
  for (int ni = 0; ni < 4; ++ni) {
    int j = ni * 16 + l15;
    float bb = bo[j];
#pragma unroll
    for (int r = 0; r < 4; ++r) {
      int qrow = qt * 64 + wave * 16 + l4 * 4 + r;
      out[((size_t)b * SS + qrow) * DD + h * 64 + j] = facc[ni][r] + bb;
    }
  }
}

// ---------------- host ----------------
extern "C" void kernel_launch(void* const* d_in, const int* in_sizes, int n_in,
                              void* d_out, int out_size, void* d_ws, size_t ws_size,
                              hipStream_t stream) {
  const float* q   = (const float*)d_in[0];
  const float* k   = (const float*)d_in[1];
  const float* v   = (const float*)d_in[2];
  const int*   mask= (const int*)d_in[3];
  const float* Wq  = (const float*)d_in[4];
  const float* bq  = (const float*)d_in[5];
  const float* Wk  = (const float*)d_in[6];
  const float* bk  = (const float*)d_in[7];
  const float* Wv  = (const float*)d_in[8];
  const float* bv  = (const float*)d_in[9];
  const float* Wqf = (const float*)d_in[10];
  const float* bqf = (const float*)d_in[11];
  const float* Wkf = (const float*)d_in[12];
  const float* bkf = (const float*)d_in[13];
  const float* Wvf = (const float*)d_in[14];
  const float* bvf = (const float*)d_in[15];
  const float* Wo  = (const float*)d_in[16];
  const float* bo  = (const float*)d_in[17];
  float* out = (float*)d_out;

  // workspace layout
  char* p = (char*)d_ws;
  __bf16* X3  = (__bf16*)p; p += (size_t)3 * MM * DD * 2;   // 24 MB
  __bf16* Wc3 = (__bf16*)p; p += (size_t)3 * DD * DD * 2;   // 6 MB
  __bf16* QKV = (__bf16*)p; p += (size_t)3 * MM * DD * 2;   // 24 MB
  float*  bc3 = (float*)p;  p += (size_t)3 * DD * 4;        // 12 KB
  if ((size_t)(p - (char*)d_ws) > ws_size) return;  // workspace too small

  prep<<<18432, 256, 0, stream>>>(q, k, v, Wq, bq, Wk, bk, Wv, bv,
                                  Wqf, bqf, Wkf, bkf, Wvf, bvf, X3, Wc3, bc3);
  gemm3<<<dim3(32, 8, 3), 256, 0, stream>>>(X3, Wc3, bc3, QKV);
  attn_kernel<<<dim3(16, 64), 256, 0, stream>>>(
      QKV, QKV + (size_t)MM * DD, QKV + (size_t)2 * MM * DD, mask, Wo, bo, out);
}